// Round 9
// baseline (1404.950 us; speedup 1.0000x reference)
//
#include <hip/hip_runtime.h>
#include <math.h>

#define BATCH 128
#define T 250
#define D_IN 700
#define H 256
#define D_OUT 20

typedef float v2f __attribute__((ext_vector_type(2)));
typedef __attribute__((ext_vector_type(8))) short bf16x8;
typedef __attribute__((ext_vector_type(4))) float f32x4;

static __device__ __forceinline__ unsigned short f2b(float f) {
    unsigned u = __float_as_uint(f);
    u += 0x7FFFu + ((u >> 16) & 1u);
    return (unsigned short)(u >> 16);
}

// ---------------------------------------------------------------------------
// Workspace layout:
//   U     [32001][256] f32   (pad row: u-prefetch overrun at t=249)
//   C1    [257][512] f32     row k, lane l: {W12T[k][4l..4l+3], W11T[k][4l..4l+3]}
//   C2    [257][512] f32     row k, lane l: {W22T[k][4l..4l+3], Wo[l&31][k],0,0,0}
//   Wi1p  [256][704] bf16    cols 700..703 zero (MFMA K-pad)
//   row 256 of C1/C2 is all-zero (spike-list padding target)
// ---------------------------------------------------------------------------
#define N_C  (257 * 512)
#define N_WP (256 * 704)

__global__ void prep_k(const float* __restrict__ Wi1, const float* __restrict__ W11,
                       const float* __restrict__ W12, const float* __restrict__ W22,
                       const float* __restrict__ Wo,
                       unsigned short* __restrict__ Wi1p, float* __restrict__ C1,
                       float* __restrict__ C2) {
    int idx = blockIdx.x * 256 + threadIdx.x;
    if (idx < N_C) {
        int k = idx >> 9, q = idx & 511;
        int l = q >> 3, jj = q & 7;
        float v = 0.f;
        if (k < H) {
            int h = 4 * l + (jj & 3);
            v = (jj < 4) ? W12[h * H + k] : W11[h * H + k];
        }
        C1[idx] = v;
        return;
    }
    idx -= N_C;
    if (idx < N_C) {
        int k = idx >> 9, q = idx & 511;
        int l = q >> 3, jj = q & 7;
        float v = 0.f;
        if (k < H) {
            if (jj < 4) v = W22[(4 * l + jj) * H + k];
            else if (jj == 4 && (l & 31) < D_OUT) v = Wo[(l & 31) * H + k];
        }
        C2[idx] = v;
        return;
    }
    idx -= N_C;
    if (idx < N_WP) {
        int h = idx / 704, k = idx - h * 704;
        Wi1p[idx] = (k < D_IN) ? f2b(Wi1[h * D_IN + k]) : (unsigned short)0;
    }
}

// ---------------------------------------------------------------------------
// U = x @ Wi1^T + bi1 via MFMA 16x16x32 bf16 (unchanged from R8).
// ---------------------------------------------------------------------------
__global__ __launch_bounds__(256) void gemm_u_k(const float* __restrict__ x,
                                                const unsigned short* __restrict__ Wi1p,
                                                const float* __restrict__ bi1,
                                                float* __restrict__ U) {
    const int lane = threadIdx.x & 63;
    const int wv = threadIdx.x >> 6;
    const int quad = lane >> 4;
    const int nl = lane & 15;
    const int mbase = blockIdx.x * 64 + wv * 16;
    const int m = mbase + nl;

    f32x4 acc[16];
#pragma unroll
    for (int i = 0; i < 16; ++i) acc[i] = (f32x4)(0.f);

    float bias[16];
#pragma unroll
    for (int nt = 0; nt < 16; ++nt) bias[nt] = bi1[nt * 16 + nl];

    const float* xrow = x + (size_t)m * D_IN;
    const unsigned short* brow = Wi1p + nl * 704 + quad * 8;

    for (int k0 = 0; k0 < 704; k0 += 32) {
        int ka = k0 + quad * 8;
        int ka2 = (ka + 4 <= 696) ? ka + 4 : 696;
        float4 q0 = *(const float4*)(xrow + ka);
        float4 q1 = *(const float4*)(xrow + ka2);
        bf16x8 af;
        af[0] = (short)f2b(q0.x); af[1] = (short)f2b(q0.y);
        af[2] = (short)f2b(q0.z); af[3] = (short)f2b(q0.w);
        af[4] = (short)f2b(q1.x); af[5] = (short)f2b(q1.y);
        af[6] = (short)f2b(q1.z); af[7] = (short)f2b(q1.w);

        const unsigned short* bp = brow + k0;
        bf16x8 bf[16];
#pragma unroll
        for (int nt = 0; nt < 16; ++nt)
            bf[nt] = *(const bf16x8*)(bp + nt * 16 * 704);
#pragma unroll
        for (int nt = 0; nt < 16; ++nt)
            acc[nt] = __builtin_amdgcn_mfma_f32_16x16x32_bf16(af, bf[nt], acc[nt], 0, 0, 0);
    }

#pragma unroll
    for (int nt = 0; nt < 16; ++nt) {
#pragma unroll
        for (int r = 0; r < 4; ++r) {
            U[(size_t)(mbase + quad * 4 + r) * H + nt * 16 + nl] = acc[nt][r] + bias[nt];
        }
    }
}

// ---------------------------------------------------------------------------
// Recurrent: 4 waves per block (one block per batch element). All waves hold
// redundant state (identical fp32 -> identical spikes); gathers split 4 ways
// using the R7 depth-2 ring + index-prefetch machinery UNCHANGED; partials
// exchanged via single-buffered LDS; exactly 2 __syncthreads per step.
// ---------------------------------------------------------------------------

__device__ __forceinline__ int build_list(unsigned int* list, int lane,
                                          float sx, float sy, float sz, float sw) {
    unsigned long long m0 = __ballot(sx > 0.f);
    unsigned long long m1 = __ballot(sy > 0.f);
    unsigned long long m2 = __ballot(sz > 0.f);
    unsigned long long m3 = __ballot(sw > 0.f);
    unsigned long long below = (1ull << lane) - 1ull;
    int c0 = __popcll(m0), c1 = __popcll(m1), c2 = __popcll(m2), c3 = __popcll(m3);
    int n = c0 + c1 + c2 + c3;
    if ((m0 >> lane) & 1) list[__popcll(m0 & below)] = lane * 4;
    if ((m1 >> lane) & 1) list[c0 + __popcll(m1 & below)] = lane * 4 + 1;
    if ((m2 >> lane) & 1) list[c0 + c1 + __popcll(m2 & below)] = lane * 4 + 2;
    if ((m3 >> lane) & 1) list[c0 + c1 + c2 + __popcll(m3 & below)] = lane * 4 + 3;
    list[n + lane] = 256;                   // 64 pad entries -> zero weight row
    __builtin_amdgcn_wave_barrier();
    return n;
}

__device__ __forceinline__ void gather_c1(const unsigned int* lst, int nb,
                                          const float* __restrict__ C,
                                          unsigned l8,
                                          v2f& A0, v2f& A1, v2f& B0, v2f& B1) {
    float4 wa0[8], wb0[8], wa1[8], wb1[8];
    {
        uint4 ia = *(const uint4*)(lst);
        uint4 ib = *(const uint4*)(lst + 4);
        unsigned I[8] = {ia.x, ia.y, ia.z, ia.w, ib.x, ib.y, ib.z, ib.w};
#pragma unroll
        for (int j = 0; j < 8; ++j) {
            const float* p = C + (I[j] << 9) + l8;
            wa0[j] = *(const float4*)(p);
            wb0[j] = *(const float4*)(p + 4);
        }
    }
    {
        uint4 ia = *(const uint4*)(lst + 8);
        uint4 ib = *(const uint4*)(lst + 12);
        unsigned I[8] = {ia.x, ia.y, ia.z, ia.w, ib.x, ib.y, ib.z, ib.w};
#pragma unroll
        for (int j = 0; j < 8; ++j) {
            const float* p = C + (I[j] << 9) + l8;
            wa1[j] = *(const float4*)(p);
            wb1[j] = *(const float4*)(p + 4);
        }
    }
    uint4 p0a = *(const uint4*)(lst + 16);
    uint4 p0b = *(const uint4*)(lst + 20);
    uint4 p1a = *(const uint4*)(lst + 24);
    uint4 p1b = *(const uint4*)(lst + 28);

    for (int b = 2; b < nb; b += 2) {
        {
            unsigned N[8] = {p0a.x, p0a.y, p0a.z, p0a.w, p0b.x, p0b.y, p0b.z, p0b.w};
#pragma unroll
            for (int j = 0; j < 8; ++j) {
                const v2f* w = (const v2f*)&wa0[j];
                A0 += w[0]; A1 += w[1];
                const v2f* v = (const v2f*)&wb0[j];
                B0 += v[0]; B1 += v[1];
                const float* p = C + (N[j] << 9) + l8;
                wa0[j] = *(const float4*)(p);
                wb0[j] = *(const float4*)(p + 4);
            }
            p0a = *(const uint4*)(lst + 8 * b + 16);
            p0b = *(const uint4*)(lst + 8 * b + 20);
        }
        {
            unsigned M[8] = {p1a.x, p1a.y, p1a.z, p1a.w, p1b.x, p1b.y, p1b.z, p1b.w};
#pragma unroll
            for (int j = 0; j < 8; ++j) {
                const v2f* w = (const v2f*)&wa1[j];
                A0 += w[0]; A1 += w[1];
                const v2f* v = (const v2f*)&wb1[j];
                B0 += v[0]; B1 += v[1];
                const float* p = C + (M[j] << 9) + l8;
                wa1[j] = *(const float4*)(p);
                wb1[j] = *(const float4*)(p + 4);
            }
            p1a = *(const uint4*)(lst + 8 * b + 24);
            p1b = *(const uint4*)(lst + 8 * b + 28);
        }
    }
#pragma unroll
    for (int j = 0; j < 8; ++j) {
        const v2f* w = (const v2f*)&wa0[j];
        A0 += w[0]; A1 += w[1];
        const v2f* v = (const v2f*)&wb0[j];
        B0 += v[0]; B1 += v[1];
    }
#pragma unroll
    for (int j = 0; j < 8; ++j) {
        const v2f* w = (const v2f*)&wa1[j];
        A0 += w[0]; A1 += w[1];
        const v2f* v = (const v2f*)&wb1[j];
        B0 += v[0]; B1 += v[1];
    }
}

__device__ __forceinline__ void gather_c2(const unsigned int* lst, int nb,
                                          const float* __restrict__ C,
                                          unsigned l8,
                                          v2f& A0, v2f& A1, float& O) {
    float4 wa0[8], wa1[8]; float o0[8], o1[8];
    {
        uint4 ia = *(const uint4*)(lst);
        uint4 ib = *(const uint4*)(lst + 4);
        unsigned I[8] = {ia.x, ia.y, ia.z, ia.w, ib.x, ib.y, ib.z, ib.w};
#pragma unroll
        for (int j = 0; j < 8; ++j) {
            const float* p = C + (I[j] << 9) + l8;
            wa0[j] = *(const float4*)(p);
            o0[j] = p[4];
        }
    }
    {
        uint4 ia = *(const uint4*)(lst + 8);
        uint4 ib = *(const uint4*)(lst + 12);
        unsigned I[8] = {ia.x, ia.y, ia.z, ia.w, ib.x, ib.y, ib.z, ib.w};
#pragma unroll
        for (int j = 0; j < 8; ++j) {
            const float* p = C + (I[j] << 9) + l8;
            wa1[j] = *(const float4*)(p);
            o1[j] = p[4];
        }
    }
    uint4 p0a = *(const uint4*)(lst + 16);
    uint4 p0b = *(const uint4*)(lst + 20);
    uint4 p1a = *(const uint4*)(lst + 24);
    uint4 p1b = *(const uint4*)(lst + 28);

    for (int b = 2; b < nb; b += 2) {
        {
            unsigned N[8] = {p0a.x, p0a.y, p0a.z, p0a.w, p0b.x, p0b.y, p0b.z, p0b.w};
#pragma unroll
            for (int j = 0; j < 8; ++j) {
                const v2f* w = (const v2f*)&wa0[j];
                A0 += w[0]; A1 += w[1];
                O += o0[j];
                const float* p = C + (N[j] << 9) + l8;
                wa0[j] = *(const float4*)(p);
                o0[j] = p[4];
            }
            p0a = *(const uint4*)(lst + 8 * b + 16);
            p0b = *(const uint4*)(lst + 8 * b + 20);
        }
        {
            unsigned M[8] = {p1a.x, p1a.y, p1a.z, p1a.w, p1b.x, p1b.y, p1b.z, p1b.w};
#pragma unroll
            for (int j = 0; j < 8; ++j) {
                const v2f* w = (const v2f*)&wa1[j];
                A0 += w[0]; A1 += w[1];
                O += o1[j];
                const float* p = C + (M[j] << 9) + l8;
                wa1[j] = *(const float4*)(p);
                o1[j] = p[4];
            }
            p1a = *(const uint4*)(lst + 8 * b + 24);
            p1b = *(const uint4*)(lst + 8 * b + 28);
        }
    }
#pragma unroll
    for (int j = 0; j < 8; ++j) {
        const v2f* w = (const v2f*)&wa0[j];
        A0 += w[0]; A1 += w[1];
        O += o0[j];
    }
#pragma unroll
    for (int j = 0; j < 8; ++j) {
        const v2f* w = (const v2f*)&wa1[j];
        A0 += w[0]; A1 += w[1];
        O += o1[j];
    }
}

__global__ __launch_bounds__(256, 1) void recurrent_k(
    const float* __restrict__ U,
    const float* __restrict__ mem1_0, const float* __restrict__ mem2_0,
    const float* __restrict__ memo_0,
    const float* __restrict__ b11v, const float* __restrict__ b12v,
    const float* __restrict__ b22v, const float* __restrict__ bov,
    const float* __restrict__ tau_adp_h1, const float* __restrict__ tau_adp_h2,
    const float* __restrict__ tau_m_h1, const float* __restrict__ tau_m_h2,
    const float* __restrict__ tau_m_o,
    const float* __restrict__ C1, const float* __restrict__ C2,
    float* __restrict__ out)
{
    const int tid = threadIdx.x;
    const int lane = tid & 63;
    const int wv = tid >> 6;                 // 0..3
    const int bi = blockIdx.x;
    const unsigned laneOff = lane * 4;
    const unsigned l8 = lane * 8;

    __shared__ __align__(16) unsigned int list1[384], list2[384];
    __shared__ __align__(16) float PG12[4][H];   // W12 partials (within-step)
    __shared__ __align__(16) float P11[4][H];    // W11 partials (carried to t+1)
    __shared__ __align__(16) float P22[4][H];    // W22 partials (carried to t+1)
    __shared__ __align__(16) float PO[4][64];    // Wo partials  (carried to t+1)

    for (int i = tid; i < 4 * H; i += 256) {
        ((float*)P11)[i] = 0.f;
        ((float*)P22)[i] = 0.f;
    }
    ((float*)PO)[tid] = 0.f;
    __syncthreads();

    // ---- redundant per-lane state in all 4 waves: neurons h = lane*4 + j
    float4 mem1 = *(const float4*)(mem1_0 + bi * H + laneOff);
    float4 mem2 = *(const float4*)(mem2_0 + bi * H + laneOff);
    float4 b1 = make_float4(0.01f, 0.01f, 0.01f, 0.01f);
    float4 b2 = make_float4(0.01f, 0.01f, 0.01f, 0.01f);
    float4 spk1 = make_float4(0.f, 0.f, 0.f, 0.f);
    float4 spk2 = make_float4(0.f, 0.f, 0.f, 0.f);

    float4 tm1 = *(const float4*)(tau_m_h1 + laneOff);
    float4 ta1 = *(const float4*)(tau_adp_h1 + laneOff);
    float4 tm2 = *(const float4*)(tau_m_h2 + laneOff);
    float4 ta2 = *(const float4*)(tau_adp_h2 + laneOff);
    float4 al1, ro1, al2, ro2;
    al1.x = expf(-1.f / tm1.x); al1.y = expf(-1.f / tm1.y);
    al1.z = expf(-1.f / tm1.z); al1.w = expf(-1.f / tm1.w);
    ro1.x = expf(-1.f / ta1.x); ro1.y = expf(-1.f / ta1.y);
    ro1.z = expf(-1.f / ta1.z); ro1.w = expf(-1.f / ta1.w);
    al2.x = expf(-1.f / tm2.x); al2.y = expf(-1.f / tm2.y);
    al2.z = expf(-1.f / tm2.z); al2.w = expf(-1.f / tm2.w);
    ro2.x = expf(-1.f / ta2.x); ro2.y = expf(-1.f / ta2.y);
    ro2.z = expf(-1.f / ta2.z); ro2.w = expf(-1.f / ta2.w);
    float4 oma1, omr1, oma2, omr2;
    oma1.x = 1.f - al1.x; oma1.y = 1.f - al1.y; oma1.z = 1.f - al1.z; oma1.w = 1.f - al1.w;
    omr1.x = 1.f - ro1.x; omr1.y = 1.f - ro1.y; omr1.z = 1.f - ro1.z; omr1.w = 1.f - ro1.w;
    oma2.x = 1.f - al2.x; oma2.y = 1.f - al2.y; oma2.z = 1.f - al2.z; oma2.w = 1.f - al2.w;
    omr2.x = 1.f - ro2.x; omr2.y = 1.f - ro2.y; omr2.z = 1.f - ro2.z; omr2.w = 1.f - ro2.w;

    float4 b11r = *(const float4*)(b11v + laneOff);
    float4 b12r = *(const float4*)(b12v + laneOff);
    float4 b22r = *(const float4*)(b22v + laneOff);
    float4 bsum2;
    bsum2.x = b12r.x + b22r.x; bsum2.y = b12r.y + b22r.y;
    bsum2.z = b12r.z + b22r.z; bsum2.w = b12r.w + b22r.w;

    float memo = 0.f, alpha_o = 0.f, bo_r = 0.f, accv = 0.f;
    if (lane < D_OUT) {
        memo = memo_0[bi * D_OUT + lane];
        alpha_o = expf(-1.f / tau_m_o[lane]);
        bo_r = bov[lane];
    }

    const float* Up = U + (size_t)bi * T * H + laneOff;
    float4 u_cur = *(const float4*)(Up);

    for (int t = 0; t < T; ++t) {
        float4 u_nxt = *(const float4*)(Up + H);   // prefetch (pad row at end)
        Up += H;

        // ---- combine carried partials from step t-1 (LDS, post barrier B)
        float4 g11c, g22c; float aOc;
        {
            float4 a0 = ((const float4*)P11[0])[lane];
            float4 a1 = ((const float4*)P11[1])[lane];
            float4 a2 = ((const float4*)P11[2])[lane];
            float4 a3 = ((const float4*)P11[3])[lane];
            g11c.x = a0.x + a1.x + a2.x + a3.x; g11c.y = a0.y + a1.y + a2.y + a3.y;
            g11c.z = a0.z + a1.z + a2.z + a3.z; g11c.w = a0.w + a1.w + a2.w + a3.w;
            float4 c0 = ((const float4*)P22[0])[lane];
            float4 c1 = ((const float4*)P22[1])[lane];
            float4 c2 = ((const float4*)P22[2])[lane];
            float4 c3 = ((const float4*)P22[3])[lane];
            g22c.x = c0.x + c1.x + c2.x + c3.x; g22c.y = c0.y + c1.y + c2.y + c3.y;
            g22c.z = c0.z + c1.z + c2.z + c3.z; g22c.w = c0.w + c1.w + c2.w + c3.w;
            aOc = PO[0][lane] + PO[1][lane] + PO[2][lane] + PO[3][lane];
        }

        // ---- deferred output for step t-1 (all waves redundant)
        if (t >= 1) {
            float o = bo_r + aOc;
            memo = memo * alpha_o + (1.f - alpha_o) * o;
            if (t >= 12) {
                float e = (lane < D_OUT) ? __expf(memo) : 0.f;
                float s = e;
#pragma unroll
                for (int d = 16; d >= 1; d >>= 1) s += __shfl_xor(s, d, 32);
                if (lane < D_OUT) accv += __fdividef(e, s);
            }
        }

        // ---- layer 1 update
        float4 h1;
        h1.x = u_cur.x + b11r.x + g11c.x; h1.y = u_cur.y + b11r.y + g11c.y;
        h1.z = u_cur.z + b11r.z + g11c.z; h1.w = u_cur.w + b11r.w + g11c.w;
        b1.x = ro1.x * b1.x + omr1.x * spk1.x; b1.y = ro1.y * b1.y + omr1.y * spk1.y;
        b1.z = ro1.z * b1.z + omr1.z * spk1.z; b1.w = ro1.w * b1.w + omr1.w * spk1.w;
        float B1x = 0.01f + 1.8f * b1.x, B1y = 0.01f + 1.8f * b1.y;
        float B1z = 0.01f + 1.8f * b1.z, B1w = 0.01f + 1.8f * b1.w;
        mem1.x = mem1.x * al1.x + oma1.x * h1.x - B1x * spk1.x;
        mem1.y = mem1.y * al1.y + oma1.y * h1.y - B1y * spk1.y;
        mem1.z = mem1.z * al1.z + oma1.z * h1.z - B1z * spk1.z;
        mem1.w = mem1.w * al1.w + oma1.w * h1.w - B1w * spk1.w;
        spk1.x = (mem1.x - B1x > 0.f) ? 1.f : 0.f;
        spk1.y = (mem1.y - B1y > 0.f) ? 1.f : 0.f;
        spk1.z = (mem1.z - B1z > 0.f) ? 1.f : 0.f;
        spk1.w = (mem1.w - B1w > 0.f) ? 1.f : 0.f;

        int n1 = build_list(list1, lane, spk1.x, spk1.y, spk1.z, spk1.w);
        int n64 = (n1 + 63) & ~63; if (n64 < 64) n64 = 64;
        int chunk1 = n64 >> 2;                  // per-wave rows, multiple of 16
        int nb1 = chunk1 >> 3;                  // even, >= 2

        v2f g12a = (v2f)(0.f), g12b = (v2f)(0.f);
        v2f g11a = (v2f)(0.f), g11b = (v2f)(0.f);
        gather_c1(list1 + wv * chunk1, nb1, C1, l8, g12a, g12b, g11a, g11b);
        ((float4*)PG12[wv])[lane] = make_float4(g12a.x, g12a.y, g12b.x, g12b.y);
        __syncthreads();                        // barrier A

        float4 g12;
        {
            float4 a0 = ((const float4*)PG12[0])[lane];
            float4 a1 = ((const float4*)PG12[1])[lane];
            float4 a2 = ((const float4*)PG12[2])[lane];
            float4 a3 = ((const float4*)PG12[3])[lane];
            g12.x = a0.x + a1.x + a2.x + a3.x; g12.y = a0.y + a1.y + a2.y + a3.y;
            g12.z = a0.z + a1.z + a2.z + a3.z; g12.w = a0.w + a1.w + a2.w + a3.w;
        }

        // ---- layer 2 update
        float4 h2;
        h2.x = bsum2.x + g22c.x + g12.x; h2.y = bsum2.y + g22c.y + g12.y;
        h2.z = bsum2.z + g22c.z + g12.z; h2.w = bsum2.w + g22c.w + g12.w;
        b2.x = ro2.x * b2.x + omr2.x * spk2.x; b2.y = ro2.y * b2.y + omr2.y * spk2.y;
        b2.z = ro2.z * b2.z + omr2.z * spk2.z; b2.w = ro2.w * b2.w + omr2.w * spk2.w;
        float B2x = 0.01f + 1.8f * b2.x, B2y = 0.01f + 1.8f * b2.y;
        float B2z = 0.01f + 1.8f * b2.z, B2w = 0.01f + 1.8f * b2.w;
        mem2.x = mem2.x * al2.x + oma2.x * h2.x - B2x * spk2.x;
        mem2.y = mem2.y * al2.y + oma2.y * h2.y - B2y * spk2.y;
        mem2.z = mem2.z * al2.z + oma2.z * h2.z - B2z * spk2.z;
        mem2.w = mem2.w * al2.w + oma2.w * h2.w - B2w * spk2.w;
        spk2.x = (mem2.x - B2x > 0.f) ? 1.f : 0.f;
        spk2.y = (mem2.y - B2y > 0.f) ? 1.f : 0.f;
        spk2.z = (mem2.z - B2z > 0.f) ? 1.f : 0.f;
        spk2.w = (mem2.w - B2w > 0.f) ? 1.f : 0.f;

        int n2 = build_list(list2, lane, spk2.x, spk2.y, spk2.z, spk2.w);
        int m64 = (n2 + 63) & ~63; if (m64 < 64) m64 = 64;
        int chunk2 = m64 >> 2;
        int nb2 = chunk2 >> 3;

        v2f g22na = (v2f)(0.f), g22nb = (v2f)(0.f);
        float aOn = 0.f;
        gather_c2(list2 + wv * chunk2, nb2, C2, l8, g22na, g22nb, aOn);

        ((float4*)P11[wv])[lane] = make_float4(g11a.x, g11a.y, g11b.x, g11b.y);
        ((float4*)P22[wv])[lane] = make_float4(g22na.x, g22na.y, g22nb.x, g22nb.y);
        PO[wv][lane] = aOn;
        u_cur = u_nxt;
        __syncthreads();                        // barrier B
    }

    // tail: finish memo(T-1) + its softmax term
    {
        float aOf = PO[0][lane] + PO[1][lane] + PO[2][lane] + PO[3][lane];
        float o = bo_r + aOf;
        memo = memo * alpha_o + (1.f - alpha_o) * o;
        float e = (lane < D_OUT) ? __expf(memo) : 0.f;
        float s = e;
#pragma unroll
        for (int d = 16; d >= 1; d >>= 1) s += __shfl_xor(s, d, 32);
        if (lane < D_OUT) accv += __fdividef(e, s);
    }

    if (tid < D_OUT) out[bi * D_OUT + tid] = accv;
}

// ---------------------------------------------------------------------------
extern "C" void kernel_launch(void* const* d_in, const int* in_sizes, int n_in,
                              void* d_out, int out_size, void* d_ws, size_t ws_size,
                              hipStream_t stream) {
    const float* x          = (const float*)d_in[0];
    const float* mem1_0     = (const float*)d_in[1];
    const float* mem2_0     = (const float*)d_in[2];
    const float* memo_0     = (const float*)d_in[3];
    const float* Wi1        = (const float*)d_in[4];
    const float* bi1        = (const float*)d_in[5];
    const float* W11        = (const float*)d_in[6];
    const float* b11        = (const float*)d_in[7];
    const float* W12        = (const float*)d_in[8];
    const float* b12        = (const float*)d_in[9];
    const float* W22        = (const float*)d_in[10];
    const float* b22        = (const float*)d_in[11];
    const float* Wo         = (const float*)d_in[12];
    const float* bo         = (const float*)d_in[13];
    const float* tau_adp_h1 = (const float*)d_in[14];
    const float* tau_adp_h2 = (const float*)d_in[15];
    const float* tau_m_h1   = (const float*)d_in[16];
    const float* tau_m_h2   = (const float*)d_in[17];
    const float* tau_m_o    = (const float*)d_in[18];

    float* U = (float*)d_ws;                            // [32001][256] f32
    float* C1 = U + ((size_t)BATCH * T + 1) * H;        // [257][512] f32
    float* C2 = C1 + N_C;                               // [257][512] f32
    unsigned short* Wi1p = (unsigned short*)(C2 + N_C); // [256][704] bf16

    int prep_total = 2 * N_C + N_WP;
    prep_k<<<(prep_total + 255) / 256, 256, 0, stream>>>(
        Wi1, W11, W12, W22, Wo, Wi1p, C1, C2);

    gemm_u_k<<<(BATCH * T) / 64, 256, 0, stream>>>(x, Wi1p, bi1, U);

    recurrent_k<<<BATCH, 256, 0, stream>>>(U, mem1_0, mem2_0, memo_0,
                                           b11, b12, b22, bo,
                                           tau_adp_h1, tau_adp_h2,
                                           tau_m_h1, tau_m_h2, tau_m_o,
                                           C1, C2, (float*)d_out);
}